// Round 15
// baseline (223.648 us; speedup 1.0000x reference)
//
#include <hip/hip_runtime.h>
#include <hip/hip_bf16.h>

#define S_LEN 2048
#define NB    32      // batch
#define EMB   1024
#define ATT   512
#define HID   1024

typedef float f32x4  __attribute__((ext_vector_type(4)));
typedef short s16x4  __attribute__((ext_vector_type(4)));
typedef short s16x8  __attribute__((ext_vector_type(8)));

static __device__ __forceinline__ short f2bf(float f) {
    return __builtin_bit_cast(short, __float2bfloat16(f));
}
static __device__ __forceinline__ float bf2f(unsigned short u) {
    unsigned int x = ((unsigned int)u) << 16;
    return __builtin_bit_cast(float, x);
}
static __device__ __forceinline__ float tanh_fast(float x) {
    float e = __expf(2.0f * x);
    return 1.0f - 2.0f / (e + 1.0f);
}

#define GLOAD_LDS16(gp, lp)                                                   \
    __builtin_amdgcn_global_load_lds(                                         \
        (const __attribute__((address_space(1))) void*)(gp),                  \
        (__attribute__((address_space(3))) void*)(uintptr_t)(lp), 16, 0, 0)

// ---------------- K_cvt: standalone emb f32 -> bf16, nontemporal both sides.
// 2048 blocks x 256 thr; 4 grid-stride groups; per group: 8 independent NT
// f32x4 loads (named regs) -> 4 NT s16x8 stores. No LDS, no barriers.
__global__ __launch_bounds__(256) void k_cvt(const float* __restrict__ emb,
                                             unsigned short* __restrict__ embB) {
    int t = threadIdx.x;
    size_t base = (size_t)blockIdx.x * 32768;   // 128 KiB of f32 per block
#pragma unroll
    for (int g = 0; g < 4; ++g) {
        size_t o = base + g * 8192 + t * 8;     // 4 rows of 2048 f32 per group
        const f32x4* p0 = (const f32x4*)(emb + o);
        const f32x4* p1 = (const f32x4*)(emb + o + 2048);
        const f32x4* p2 = (const f32x4*)(emb + o + 4096);
        const f32x4* p3 = (const f32x4*)(emb + o + 6144);
        f32x4 a0 = __builtin_nontemporal_load(p0);
        f32x4 a1 = __builtin_nontemporal_load(p0 + 1);
        f32x4 b0 = __builtin_nontemporal_load(p1);
        f32x4 b1 = __builtin_nontemporal_load(p1 + 1);
        f32x4 c0 = __builtin_nontemporal_load(p2);
        f32x4 c1 = __builtin_nontemporal_load(p2 + 1);
        f32x4 d0 = __builtin_nontemporal_load(p3);
        f32x4 d1 = __builtin_nontemporal_load(p3 + 1);
        s16x8 r0, r1, r2, r3;
        r0[0] = f2bf(a0[0]); r0[1] = f2bf(a0[1]); r0[2] = f2bf(a0[2]); r0[3] = f2bf(a0[3]);
        r0[4] = f2bf(a1[0]); r0[5] = f2bf(a1[1]); r0[6] = f2bf(a1[2]); r0[7] = f2bf(a1[3]);
        r1[0] = f2bf(b0[0]); r1[1] = f2bf(b0[1]); r1[2] = f2bf(b0[2]); r1[3] = f2bf(b0[3]);
        r1[4] = f2bf(b1[0]); r1[5] = f2bf(b1[1]); r1[6] = f2bf(b1[2]); r1[7] = f2bf(b1[3]);
        r2[0] = f2bf(c0[0]); r2[1] = f2bf(c0[1]); r2[2] = f2bf(c0[2]); r2[3] = f2bf(c0[3]);
        r2[4] = f2bf(c1[0]); r2[5] = f2bf(c1[1]); r2[6] = f2bf(c1[2]); r2[7] = f2bf(c1[3]);
        r3[0] = f2bf(d0[0]); r3[1] = f2bf(d0[1]); r3[2] = f2bf(d0[2]); r3[3] = f2bf(d0[3]);
        r3[4] = f2bf(d1[0]); r3[5] = f2bf(d1[1]); r3[6] = f2bf(d1[2]); r3[7] = f2bf(d1[3]);
        __builtin_nontemporal_store(r0, (s16x8*)(embB + o));
        __builtin_nontemporal_store(r1, (s16x8*)(embB + o + 2048));
        __builtin_nontemporal_store(r2, (s16x8*)(embB + o + 4096));
        __builtin_nontemporal_store(r3, (s16x8*)(embB + o + 6144));
    }
}

// ---------------- K_hw: {hid_comb | W_emb^T->bf16}
__global__ void k_hw(const float* __restrict__ hid,
                     const float* __restrict__ W_hid,
                     const float* __restrict__ b_hid,
                     const float* __restrict__ W_emb,
                     const float* __restrict__ b_emb,
                     float* __restrict__ hid_comb,
                     unsigned short* __restrict__ WT) {
    __shared__ __align__(16) char lds[8192];
    int blk = blockIdx.x, tid = threadIdx.x;
    if (blk < 64) {
        // hid_comb[b][a] = hid[b,:]@W_hid[:,a] + b_hid[a] + b_emb[a]
        f32x4 (*red)[64] = (f32x4(*)[64])lds;   // [4 ks][64 al]
        int b    = blk >> 1;
        int a4   = (tid & 63) * 4 + (blk & 1) * 256;
        int ks   = tid >> 6;                    // k-slice 0..3
        int k0   = ks * 256;
        const float* hr = hid + b * HID + k0;
        const float* wp = W_hid + (size_t)k0 * ATT + a4;
        f32x4 acc = {0.f, 0.f, 0.f, 0.f};
        for (int kb = 0; kb < 256; kb += 8) {
            f32x4 x[8];
#pragma unroll
            for (int u = 0; u < 8; ++u)
                x[u] = *(const f32x4*)(wp + (size_t)(kb + u) * ATT);
            float h[8];
#pragma unroll
            for (int u = 0; u < 8; ++u) h[u] = hr[kb + u];
#pragma unroll
            for (int u = 0; u < 8; ++u) acc += h[u] * x[u];
        }
        red[ks][tid & 63] = acc;
        __syncthreads();
        if (ks == 0) {
            int al = tid & 63;
            f32x4 s = acc + red[1][al] + red[2][al] + red[3][al];
            f32x4 bh = *(const f32x4*)(b_hid + a4);
            f32x4 be = *(const f32x4*)(b_emb + a4);
            *(f32x4*)(hid_comb + b * ATT + a4) = s + bh + be;
        }
    } else {
        // WT[a][k] = bf16(W_emb[k][a])
        float (*tile)[33] = (float(*)[33])lds;
        int b2 = blk - 64;
        int k0 = (b2 & 31) * 32, a0 = (b2 >> 5) * 32;
        int tx = tid & 31, ty = tid >> 5;   // 32 x 8
#pragma unroll
        for (int i = 0; i < 32; i += 8)
            tile[ty + i][tx] = W_emb[(size_t)(k0 + ty + i) * ATT + a0 + tx];
        __syncthreads();
#pragma unroll
        for (int i = 0; i < 32; i += 8)
            WT[(size_t)(a0 + ty + i) * HID + k0 + tx] =
                (unsigned short)f2bf(tile[tx][ty + i]);
    }
}

// ---------------- K3: 256x256 8-phase GEMM, BOTH operands via global_load_lds
// (bf16, pre-swizzled source, linear LDS dest). 512 thr = 8 waves (2M x 4N),
// wave tile 128x64. BK=64, 16 K-tiles, 4 phases/tile, 2 gloads/phase.
// ONE counted vmcnt(2) per K-tile; lgkmcnt(0)+sched_barrier per rule #18.
// Quadrant MFMA order reuses operands: reads 12/4/8/0 b128 per phase.
__global__ __launch_bounds__(512) void k_gemm_scores(
        const unsigned short* __restrict__ embB,
        const unsigned short* __restrict__ WT,
        const float* __restrict__ hid_comb,
        const float* __restrict__ att_v,
        float* __restrict__ part) {
    // [A0 32K][A1 32K][B0 32K][B1 32K]; each buf = [2 halves][128 rows][64 k]bf16
    __shared__ __align__(16) unsigned short ldsbuf[65536];   // 128 KB
    char* L = (char*)ldsbuf;

    int bid = blockIdx.x;                    // 512 wgs = 256 mt x 2 nt
    int t2  = (bid & 7) * 64 + (bid >> 3);   // XCD swizzle (512%8==0 bijective)
    int mt  = t2 >> 1, nt = t2 & 1;
    int m0  = mt * 256, n0 = nt * 256;

    int tid  = threadIdx.x;
    int lane = tid & 63, wv = tid >> 6;
    int wm = wv >> 2, wn = wv & 3;           // wave tile rows wm*128, cols wn*64
    int row_l = lane & 15, kg = lane >> 4;

    // ---- staging maps (identical for A and B): per half, 1024 chunks, 2/thread
    int row0 = tid >> 3, pos0 = tid & 7;     // chunk j=0 ; j=1 -> row0+64, same pos
    int dst0 = tid * 16, dst1 = tid * 16 + 8192;
    const unsigned short* aG[2][2];
    const unsigned short* bG[2][2];
#pragma unroll
    for (int h = 0; h < 2; ++h) {
        aG[h][0] = embB + (size_t)(m0 + h * 128 + row0) * EMB + ((pos0 ^ (row0 & 7)) * 8);
        aG[h][1] = embB + (size_t)(m0 + h * 128 + row0 + 64) * EMB + ((pos0 ^ (row0 & 7)) * 8);
        bG[h][0] = WT   + (size_t)(n0 + h * 128 + row0) * HID + ((pos0 ^ (row0 & 7)) * 8);
        bG[h][1] = WT   + (size_t)(n0 + h * 128 + row0 + 64) * HID + ((pos0 ^ (row0 & 7)) * 8);
    }

    // ---- fragment read offsets
    int aoff[8], boff[4], cx[2];
#pragma unroll
    for (int mf = 0; mf < 8; ++mf)
        aoff[mf] = wm * 16384 + (mf * 16 + row_l) * 128;
#pragma unroll
    for (int nf = 0; nf < 4; ++nf)
        boff[nf] = 65536 + (wn >> 1) * 16384 + (((wn & 1) * 64 + nf * 16 + row_l)) * 128;
#pragma unroll
    for (int ks = 0; ks < 2; ++ks)
        cx[ks] = ((ks * 4 + kg) ^ (row_l & 7)) * 16;

    f32x4 acc[8][4] = {};

#define STAGE_A(H, KT, BUF)                                                    \
    GLOAD_LDS16(aG[H][0] + (KT), L + (BUF) * 32768 + (H) * 16384 + dst0);      \
    GLOAD_LDS16(aG[H][1] + (KT), L + (BUF) * 32768 + (H) * 16384 + dst1);
#define STAGE_B(H, KT, BUF)                                                    \
    GLOAD_LDS16(bG[H][0] + (KT), L + 65536 + (BUF) * 32768 + (H) * 16384 + dst0); \
    GLOAD_LDS16(bG[H][1] + (KT), L + 65536 + (BUF) * 32768 + (H) * 16384 + dst1);

#define QUAD(MB, NBASE, AF, BF)                                                \
    _Pragma("unroll")                                                          \
    for (int ml = 0; ml < 4; ++ml)                                             \
        _Pragma("unroll")                                                      \
        for (int nl = 0; nl < 2; ++nl)                                         \
            _Pragma("unroll")                                                  \
            for (int ks = 0; ks < 2; ++ks)                                     \
                acc[(MB) + ml][(NBASE) + nl] =                                 \
                    __builtin_amdgcn_mfma_f32_16x16x32_bf16(                   \
                        AF[ml][ks], BF[nl][ks], acc[(MB) + ml][(NBASE) + nl],  \
                        0, 0, 0);

    // ---- prologue: tile 0 -> buf0 (8 loads)
    STAGE_A(0, 0, 0) STAGE_A(1, 0, 0) STAGE_B(0, 0, 0) STAGE_B(1, 0, 0)

    for (int t = 0; t < 16; ++t) {
        int bt = t & 1, bn = bt ^ 1;
        int btA = bt * 32768;
        int ktn = ((t + 1) & 15) * 64;
        s16x8 af[4][2], af2[4][2], bfA[2][2], bfB[2][2];

        // ---- P0: stage A-h0(t+1); wait tile t ready; Q0 = (mf0-3, nf0-1)
        STAGE_A(0, ktn, bn)
        asm volatile("s_waitcnt vmcnt(2)" ::: "memory");
        asm volatile("s_barrier" ::: "memory");
#pragma unroll
        for (int ml = 0; ml < 4; ++ml)
#pragma unroll
            for (int ks = 0; ks < 2; ++ks)
                af[ml][ks] = *(const s16x8*)(L + btA + aoff[ml] + cx[ks]);
#pragma unroll
        for (int nl = 0; nl < 2; ++nl)
#pragma unroll
            for (int ks = 0; ks < 2; ++ks)
                bfA[nl][ks] = *(const s16x8*)(L + btA + boff[nl] + cx[ks]);
        asm volatile("s_waitcnt lgkmcnt(0)" ::: "memory");
        __builtin_amdgcn_sched_barrier(0);
        __builtin_amdgcn_s_setprio(1);
        QUAD(0, 0, af, bfA)
        __builtin_amdgcn_s_setprio(0);
        asm volatile("s_barrier" ::: "memory");

        // ---- P1: stage A-h1(t+1); Q1 = (mf0-3, nf2-3), reuse af
        STAGE_A(1, ktn, bn)
#pragma unroll
        for (int nl = 0; nl < 2; ++nl)
#pragma unroll
            for (int ks = 0; ks < 2; ++ks)
                bfB[nl][ks] = *(const s16x8*)(L + btA + boff[2 + nl] + cx[ks]);
        asm volatile("s_waitcnt lgkmcnt(0)" ::: "memory");
        __builtin_amdgcn_sched_barrier(0);
        __builtin_amdgcn_s_setprio(1);
        QUAD(0, 2, af, bfB)
        __builtin_amdgcn_s_setprio(0);
        asm volatile("s_barrier" ::: "memory");

        // ---- P2: stage B-h0(t+1); Q2 = (mf4-7, nf2-3), reuse bfB
        STAGE_B(0, ktn, bn)
#pragma unroll
        for (int ml = 0; ml < 4; ++ml)
#pragma unroll
            for (int ks = 0; ks < 2; ++ks)
                af2[ml][ks] = *(const s16x8*)(L + btA + aoff[4 + ml] + cx[ks]);
        asm volatile("s_waitcnt lgkmcnt(0)" ::: "memory");
        __builtin_amdgcn_sched_barrier(0);
        __builtin_amdgcn_s_setprio(1);
        QUAD(4, 2, af2, bfB)
        __builtin_amdgcn_s_setprio(0);
        asm volatile("s_barrier" ::: "memory");

        // ---- P3: stage B-h1(t+1); Q3 = (mf4-7, nf0-1), reuse af2 + bfA
        STAGE_B(1, ktn, bn)
        __builtin_amdgcn_s_setprio(1);
        QUAD(4, 0, af2, bfA)
        __builtin_amdgcn_s_setprio(0);
        asm volatile("s_barrier" ::: "memory");
    }
#undef STAGE_A
#undef STAGE_B
#undef QUAD

    // ---- epilogue: tanh + dot(att_v) + 16-lane reduce -> 8 score slices
    float vvv[4];
#pragma unroll
    for (int nf = 0; nf < 4; ++nf)
        vvv[nf] = att_v[n0 + wn * 64 + nf * 16 + row_l];

    int slice = nt * 4 + wn;
#pragma unroll
    for (int mf = 0; mf < 8; ++mf) {
#pragma unroll
        for (int j = 0; j < 4; ++j) {
            int m = m0 + wm * 128 + mf * 16 + kg * 4 + j;   // D row
            int b = m & 31;
            int s = m >> 5;
            const float* ad = hid_comb + b * ATT + n0 + wn * 64;
            float sum = 0.f;
#pragma unroll
            for (int nf = 0; nf < 4; ++nf) {
                float xv = acc[mf][nf][j] + ad[nf * 16 + row_l];
                sum += tanh_fast(xv) * vvv[nf];
            }
#pragma unroll
            for (int d = 1; d < 16; d <<= 1)
                sum += __shfl_xor(sum, d, 64);
            if (row_l == 0)
                part[slice * (NB * S_LEN) + b * S_LEN + s] = sum;
        }
    }
}

// ---------------- K_ctx1s: fused softmax (recomputed per block) + context
// grid (16 schunks, 32 b) x 256 thr; reads bf16 embB; writes weights (sc==0)
__global__ void k_ctx1s(const unsigned short* __restrict__ embB,
                        const float* __restrict__ part,
                        float* __restrict__ weights,
                        float* __restrict__ cpart) {
    int sc = blockIdx.x, b = blockIdx.y, t = threadIdx.x;
    __shared__ float sm[4], ss[4], wl[128];

    // softmax over all 2048 (each thread owns s = i*256+t)
    float v[8];
    float mx = -1e30f;
#pragma unroll
    for (int i = 0; i < 8; ++i) {
        int s = i * 256 + t;
        float x = 0.f;
#pragma unroll
        for (int p = 0; p < 8; ++p)
            x += part[p * (NB * S_LEN) + b * S_LEN + s];
        v[i] = x;
        mx = fmaxf(mx, x);
    }
#pragma unroll
    for (int d = 1; d < 64; d <<= 1) mx = fmaxf(mx, __shfl_xor(mx, d, 64));
    if ((t & 63) == 0) sm[t >> 6] = mx;
    __syncthreads();
    mx = fmaxf(fmaxf(sm[0], sm[1]), fmaxf(sm[2], sm[3]));
    float sum = 0.f;
#pragma unroll
    for (int i = 0; i < 8; ++i) {
        v[i] = __expf(v[i] - mx);
        sum += v[i];
    }
#pragma unroll
    for (int d = 1; d < 64; d <<= 1) sum += __shfl_xor(sum, d, 64);
    if ((t & 63) == 0) ss[t >> 6] = sum;
    __syncthreads();
    sum = ss[0] + ss[1] + ss[2] + ss[3];
    float inv = 1.0f / sum;

    // stash this block's 128-s window of weights; write d_out from sc==0
    if ((t >> 7) == (sc & 1)) wl[t & 127] = v[sc >> 1] * inv;
    if (sc == 0) {
#pragma unroll
        for (int i = 0; i < 8; ++i)
            weights[b * S_LEN + i * 256 + t] = v[i] * inv;
    }
    __syncthreads();

    // context partial over this s-window (bf16 emb)
    int par = t >> 7;
    int e0 = (t & 127) * 8;
    float acc[8] = {};
    for (int i = 0; i < 128; i += 2) {
        int s = sc * 128 + i + par;
        float w = wl[i + par];
        s16x8 x = *(const s16x8*)(embB + (((size_t)(s * NB + b)) << 10) + e0);
#pragma unroll
        for (int u = 0; u < 8; ++u)
            acc[u] += w * bf2f((unsigned short)x[u]);
    }
    float* dst = cpart + ((size_t)(sc * 2 + par) * NB + b) * EMB + e0;
    f32x4 lo = {acc[0], acc[1], acc[2], acc[3]};
    f32x4 hi = {acc[4], acc[5], acc[6], acc[7]};
    *(f32x4*)(dst)     = lo;
    *(f32x4*)(dst + 4) = hi;
}

// ---------------- K_ctx2: reduce 32 partials -> context (d_out front)
__global__ void k_ctx2(const float* __restrict__ cpart, float* __restrict__ ctx) {
    int i = blockIdx.x * 256 + threadIdx.x;   // 32*1024
    float s = 0.f;
#pragma unroll
    for (int p = 0; p < 32; ++p) s += cpart[(size_t)p * (NB * EMB) + i];
    ctx[i] = s;
}

extern "C" void kernel_launch(void* const* d_in, const int* in_sizes, int n_in,
                              void* d_out, int out_size, void* d_ws, size_t ws_size,
                              hipStream_t stream) {
    const float* hid   = (const float*)d_in[0];
    const float* emb   = (const float*)d_in[1];
    const float* W_hid = (const float*)d_in[2];
    const float* b_hid = (const float*)d_in[3];
    const float* W_emb = (const float*)d_in[4];
    const float* b_emb = (const float*)d_in[5];
    const float* att_v = (const float*)d_in[6];

    float* out     = (float*)d_out;
    float* ctx     = out;                // 32*1024
    float* weights = out + NB * EMB;     // 32*2048

    char* ws = (char*)d_ws;
    float*          part     = (float*)(ws);                    // 2 MiB
    float*          hid_comb = (float*)(ws + 2097152);          // 64 KiB
    unsigned short* WT       = (unsigned short*)(ws + 2162688); // 1 MiB
    unsigned short* embB     = (unsigned short*)(ws + 3211264); // 128 MiB
    float*          cpart    = (float*)(ws + 137428992);        // 4 MiB

    k_hw<<<576, 256, 0, stream>>>(hid, W_hid, b_hid, W_emb, b_emb, hid_comb, WT);
    k_cvt<<<2048, 256, 0, stream>>>(emb, embB);
    k_gemm_scores<<<512, 512, 0, stream>>>(embB, WT, hid_comb, att_v, part);
    k_ctx1s<<<dim3(16, NB), 256, 0, stream>>>(embB, part, weights, cpart);
    k_ctx2<<<128, 256, 0, stream>>>(cpart, ctx);
}

// Round 16
// 196.717 us; speedup vs baseline: 1.1369x; 1.1369x over previous
//
#include <hip/hip_runtime.h>
#include <hip/hip_bf16.h>

#define S_LEN 2048
#define NB    32      // batch
#define EMB   1024
#define ATT   512
#define HID   1024

typedef float f32x4  __attribute__((ext_vector_type(4)));
typedef short s16x4  __attribute__((ext_vector_type(4)));
typedef short s16x8  __attribute__((ext_vector_type(8)));

static __device__ __forceinline__ short f2bf(float f) {
    return __builtin_bit_cast(short, __float2bfloat16(f));
}
static __device__ __forceinline__ float tanh_fast(float x) {
    float e = __expf(2.0f * x);
    return 1.0f - 2.0f / (e + 1.0f);
}

#define GLOAD_LDS16(gp, lp)                                                   \
    __builtin_amdgcn_global_load_lds(                                         \
        (const __attribute__((address_space(1))) void*)(gp),                  \
        (__attribute__((address_space(3))) void*)(uintptr_t)(lp), 16, 0, 0)

#define ORDER_FENCE() asm volatile("" ::: "memory")

// ---------------- K_hw: {hid_comb | W_emb^T->bf16}
__global__ void k_hw(const float* __restrict__ hid,
                     const float* __restrict__ W_hid,
                     const float* __restrict__ b_hid,
                     const float* __restrict__ W_emb,
                     const float* __restrict__ b_emb,
                     float* __restrict__ hid_comb,
                     unsigned short* __restrict__ WT) {
    __shared__ __align__(16) char lds[8192];
    int blk = blockIdx.x, tid = threadIdx.x;
    if (blk < 64) {
        // hid_comb[b][a] = hid[b,:]@W_hid[:,a] + b_hid[a] + b_emb[a]
        f32x4 (*red)[64] = (f32x4(*)[64])lds;   // [4 ks][64 al]
        int b    = blk >> 1;
        int a4   = (tid & 63) * 4 + (blk & 1) * 256;
        int ks   = tid >> 6;                    // k-slice 0..3
        int k0   = ks * 256;
        const float* hr = hid + b * HID + k0;
        const float* wp = W_hid + (size_t)k0 * ATT + a4;
        f32x4 acc = {0.f, 0.f, 0.f, 0.f};
        for (int kb = 0; kb < 256; kb += 8) {
            f32x4 x[8];
#pragma unroll
            for (int u = 0; u < 8; ++u)
                x[u] = *(const f32x4*)(wp + (size_t)(kb + u) * ATT);
            float h[8];
#pragma unroll
            for (int u = 0; u < 8; ++u) h[u] = hr[kb + u];
#pragma unroll
            for (int u = 0; u < 8; ++u) acc += h[u] * x[u];
        }
        red[ks][tid & 63] = acc;
        __syncthreads();
        if (ks == 0) {
            int al = tid & 63;
            f32x4 s = acc + red[1][al] + red[2][al] + red[3][al];
            f32x4 bh = *(const f32x4*)(b_hid + a4);
            f32x4 be = *(const f32x4*)(b_emb + a4);
            *(f32x4*)(hid_comb + b * ATT + a4) = s + bh + be;
        }
    } else {
        // WT[a][k] = bf16(W_emb[k][a])
        float (*tile)[33] = (float(*)[33])lds;
        int b2 = blk - 64;
        int k0 = (b2 & 31) * 32, a0 = (b2 >> 5) * 32;
        int tx = tid & 31, ty = tid >> 5;   // 32 x 8
#pragma unroll
        for (int i = 0; i < 32; i += 8)
            tile[ty + i][tx] = W_emb[(size_t)(k0 + ty + i) * ATT + a0 + tx];
        __syncthreads();
#pragma unroll
        for (int i = 0; i < 32; i += 8)
            WT[(size_t)(a0 + ty + i) * HID + k0 + tx] =
                (unsigned short)f2bf(tile[tx][ty + i]);
    }
}

// ---------------- K3: 256x256 8-phase GEMM, f32 A consumed DIRECTLY.
// A: reg-load f32 (2 K-tiles ahead) -> RNE cvt -> swizzled ds_write bf16;
// B: global_load_lds bf16 (pre-swizzled source). LDS layout/frag reads/MFMA
// schedule identical to the proven bf16 version. Waits derived from VMEM
// issue order (12/tile: B2,B2,Rh0x4,Rh1x4): P0 vmcnt(10), P2/P3 vmcnt(8).
__global__ __launch_bounds__(512) void k_gemm_scores(
        const float* __restrict__ emb,
        const unsigned short* __restrict__ WT,
        const float* __restrict__ hid_comb,
        const float* __restrict__ att_v,
        float* __restrict__ part) {
    // [A0 32K][A1 32K][B0 32K][B1 32K]; each buf = [2 halves][128 rows][64 k]bf16
    __shared__ __align__(16) unsigned short ldsbuf[65536];   // 128 KB
    char* L = (char*)ldsbuf;

    int bid = blockIdx.x;                    // 512 wgs = 256 mt x 2 nt
    int t2  = (bid & 7) * 64 + (bid >> 3);   // XCD swizzle; nt-pair same XCD
    int mt  = t2 >> 1, nt = t2 & 1;
    int m0  = mt * 256, n0 = nt * 256;

    int tid  = threadIdx.x;
    int lane = tid & 63, wv = tid >> 6;
    int wm = wv >> 2, wn = wv & 3;           // wave tile rows wm*128, cols wn*64
    int row_l = lane & 15, kg = lane >> 4;

    // ---- A staging map: per half, thread covers rows ar, ar+64 at 8-f32 pos ap
    int ar = tid >> 3, ap = tid & 7;
    const float* aG0 = emb + (size_t)(m0 + ar) * EMB + ap * 8;         // h0
    const float* aG1 = emb + (size_t)(m0 + 128 + ar) * EMB + ap * 8;   // h1
    int axor = (ap ^ (ar & 7)) * 16;
    int da0 = ar * 128 + axor;               // + h*16384 + buf*32768
    int da1 = (ar + 64) * 128 + axor;        // (ar+64)&7 == ar&7: same xor

    // ---- B staging map (pre-swizzled source, linear LDS dest)
    int row0 = tid >> 3, pos0 = tid & 7;
    int dst0 = tid * 16, dst1 = tid * 16 + 8192;
    const unsigned short* bG[2][2];
#pragma unroll
    for (int h = 0; h < 2; ++h) {
        bG[h][0] = WT + (size_t)(n0 + h * 128 + row0) * HID + ((pos0 ^ (row0 & 7)) * 8);
        bG[h][1] = WT + (size_t)(n0 + h * 128 + row0 + 64) * HID + ((pos0 ^ (row0 & 7)) * 8);
    }

    // ---- fragment read offsets
    int aoff[8], boff[4], cx[2];
#pragma unroll
    for (int mf = 0; mf < 8; ++mf)
        aoff[mf] = wm * 16384 + (mf * 16 + row_l) * 128;
#pragma unroll
    for (int nf = 0; nf < 4; ++nf)
        boff[nf] = 65536 + (wn >> 1) * 16384 + (((wn & 1) * 64 + nf * 16 + row_l)) * 128;
#pragma unroll
    for (int ks = 0; ks < 2; ++ks)
        cx[ks] = ((ks * 4 + kg) ^ (row_l & 7)) * 16;

    f32x4 acc[8][4] = {};
    f32x4 Rh0[4], Rh1[4];     // A stage regs, 2 K-tiles ahead (static names)

#define LOAD_RH(RH, SRC, KT)                                                   \
    RH[0] = *(const f32x4*)((SRC) + (KT));                                     \
    RH[1] = *(const f32x4*)((SRC) + (KT) + 4);                                 \
    RH[2] = *(const f32x4*)((SRC) + (KT) + 64 * EMB);                          \
    RH[3] = *(const f32x4*)((SRC) + (KT) + 64 * EMB + 4);

#define CVT_WRITE_A(RH, OFF)                                                   \
    {                                                                          \
        s16x8 v0, v1;                                                          \
        v0[0] = f2bf(RH[0][0]); v0[1] = f2bf(RH[0][1]);                        \
        v0[2] = f2bf(RH[0][2]); v0[3] = f2bf(RH[0][3]);                        \
        v0[4] = f2bf(RH[1][0]); v0[5] = f2bf(RH[1][1]);                        \
        v0[6] = f2bf(RH[1][2]); v0[7] = f2bf(RH[1][3]);                        \
        v1[0] = f2bf(RH[2][0]); v1[1] = f2bf(RH[2][1]);                        \
        v1[2] = f2bf(RH[2][2]); v1[3] = f2bf(RH[2][3]);                        \
        v1[4] = f2bf(RH[3][0]); v1[5] = f2bf(RH[3][1]);                        \
        v1[6] = f2bf(RH[3][2]); v1[7] = f2bf(RH[3][3]);                        \
        *(s16x8*)(L + (OFF) + da0) = v0;                                       \
        *(s16x8*)(L + (OFF) + da1) = v1;                                       \
    }

#define STAGE_B(H, KT, BUF)                                                    \
    GLOAD_LDS16(bG[H][0] + (KT), L + 65536 + (BUF) * 32768 + (H) * 16384 + dst0); \
    GLOAD_LDS16(bG[H][1] + (KT), L + 65536 + (BUF) * 32768 + (H) * 16384 + dst1);

#define QUAD(MB, NBASE, AF, BF)                                                \
    _Pragma("unroll")                                                          \
    for (int ml = 0; ml < 4; ++ml)                                             \
        _Pragma("unroll")                                                      \
        for (int nl = 0; nl < 2; ++nl)                                         \
            _Pragma("unroll")                                                  \
            for (int ks = 0; ks < 2; ++ks)                                     \
                acc[(MB) + ml][(NBASE) + nl] =                                 \
                    __builtin_amdgcn_mfma_f32_16x16x32_bf16(                   \
                        AF[ml][ks], BF[nl][ks], acc[(MB) + ml][(NBASE) + nl],  \
                        0, 0, 0);

    // ---- prologue: B(0)->Bbuf0; A(0) regs->cvt->Abuf0; A(1)->regs
    STAGE_B(0, 0, 0) STAGE_B(1, 0, 0)
    ORDER_FENCE();
    LOAD_RH(Rh0, aG0, 0) LOAD_RH(Rh1, aG1, 0)
    asm volatile("s_waitcnt vmcnt(0)" ::: "memory");
    CVT_WRITE_A(Rh0, 0)
    CVT_WRITE_A(Rh1, 16384)
    ORDER_FENCE();
    LOAD_RH(Rh0, aG0, 64) LOAD_RH(Rh1, aG1, 64)
    asm volatile("s_waitcnt lgkmcnt(0)\n\ts_barrier" ::: "memory");

    for (int t = 0; t < 16; ++t) {
        int bt = t & 1, bn = bt ^ 1;
        int btA = bt * 32768;
        int ktn = ((t + 1) & 15) * 64;
        int kta = ((t + 2) & 15) * 64;
        s16x8 af[4][2], af2[4][2], bfA[2][2], bfB[2][2];

        // ---- P0: stage B(t+1)h0; wait B(t) (vmcnt 10); Q0 = (mf0-3, nf0-1)
        STAGE_B(0, ktn, bn)
        asm volatile("s_waitcnt vmcnt(10)" ::: "memory");
        asm volatile("s_barrier" ::: "memory");
#pragma unroll
        for (int ml = 0; ml < 4; ++ml)
#pragma unroll
            for (int ks = 0; ks < 2; ++ks)
                af[ml][ks] = *(const s16x8*)(L + btA + aoff[ml] + cx[ks]);
#pragma unroll
        for (int nl = 0; nl < 2; ++nl)
#pragma unroll
            for (int ks = 0; ks < 2; ++ks)
                bfA[nl][ks] = *(const s16x8*)(L + btA + boff[nl] + cx[ks]);
        asm volatile("s_waitcnt lgkmcnt(0)" ::: "memory");
        __builtin_amdgcn_sched_barrier(0);
        __builtin_amdgcn_s_setprio(1);
        QUAD(0, 0, af, bfA)
        __builtin_amdgcn_s_setprio(0);
        asm volatile("s_barrier" ::: "memory");

        // ---- P1: stage B(t+1)h1; Q1 = (mf0-3, nf2-3), reuse af
        STAGE_B(1, ktn, bn)
#pragma unroll
        for (int nl = 0; nl < 2; ++nl)
#pragma unroll
            for (int ks = 0; ks < 2; ++ks)
                bfB[nl][ks] = *(const s16x8*)(L + btA + boff[2 + nl] + cx[ks]);
        asm volatile("s_waitcnt lgkmcnt(0)" ::: "memory");
        __builtin_amdgcn_sched_barrier(0);
        __builtin_amdgcn_s_setprio(1);
        QUAD(0, 2, af, bfB)
        __builtin_amdgcn_s_setprio(0);
        asm volatile("s_barrier" ::: "memory");

        // ---- P2: Rh0(t+1) ready (vmcnt 8); cvt+write h0->bn; reload Rh0(t+2);
        //          Q2 = (mf4-7, nf2-3), reuse bfB
        asm volatile("s_waitcnt vmcnt(8)" ::: "memory");
        CVT_WRITE_A(Rh0, bn * 32768)
        ORDER_FENCE();
        LOAD_RH(Rh0, aG0, kta)
        ORDER_FENCE();
#pragma unroll
        for (int ml = 0; ml < 4; ++ml)
#pragma unroll
            for (int ks = 0; ks < 2; ++ks)
                af2[ml][ks] = *(const s16x8*)(L + btA + aoff[4 + ml] + cx[ks]);
        asm volatile("s_waitcnt lgkmcnt(0)" ::: "memory");
        __builtin_amdgcn_sched_barrier(0);
        __builtin_amdgcn_s_setprio(1);
        QUAD(4, 2, af2, bfB)
        __builtin_amdgcn_s_setprio(0);
        asm volatile("s_barrier" ::: "memory");

        // ---- P3: Rh1(t+1) ready (vmcnt 8); cvt+write h1->bn; reload Rh1(t+2);
        //          Q3 = (mf4-7, nf0-1), reuse af2+bfA; drain writes pre-barrier
        asm volatile("s_waitcnt vmcnt(8)" ::: "memory");
        CVT_WRITE_A(Rh1, bn * 32768 + 16384)
        ORDER_FENCE();
        LOAD_RH(Rh1, aG1, kta)
        ORDER_FENCE();
        __builtin_amdgcn_s_setprio(1);
        QUAD(4, 0, af2, bfA)
        __builtin_amdgcn_s_setprio(0);
        asm volatile("s_waitcnt lgkmcnt(0)\n\ts_barrier" ::: "memory");
    }
#undef LOAD_RH
#undef CVT_WRITE_A
#undef STAGE_B
#undef QUAD

    // ---- epilogue: tanh + dot(att_v) + 16-lane reduce -> 8 score slices
    float vvv[4];
#pragma unroll
    for (int nf = 0; nf < 4; ++nf)
        vvv[nf] = att_v[n0 + wn * 64 + nf * 16 + row_l];

    int slice = nt * 4 + wn;
#pragma unroll
    for (int mf = 0; mf < 8; ++mf) {
#pragma unroll
        for (int j = 0; j < 4; ++j) {
            int m = m0 + wm * 128 + mf * 16 + kg * 4 + j;   // D row
            int b = m & 31;
            int s = m >> 5;
            const float* ad = hid_comb + b * ATT + n0 + wn * 64;
            float sum = 0.f;
#pragma unroll
            for (int nf = 0; nf < 4; ++nf) {
                float xv = acc[mf][nf][j] + ad[nf * 16 + row_l];
                sum += tanh_fast(xv) * vvv[nf];
            }
#pragma unroll
            for (int d = 1; d < 16; d <<= 1)
                sum += __shfl_xor(sum, d, 64);
            if (row_l == 0)
                part[slice * (NB * S_LEN) + b * S_LEN + s] = sum;
        }
    }
}

// ---------------- K_ctx1s: fused softmax (recomputed per block) + context
// grid (16 schunks, 32 b) x 256 thr; reads f32 emb (L3-warm after gemm)
__global__ void k_ctx1s(const float* __restrict__ emb,
                        const float* __restrict__ part,
                        float* __restrict__ weights,
                        float* __restrict__ cpart) {
    int sc = blockIdx.x, b = blockIdx.y, t = threadIdx.x;
    __shared__ float sm[4], ss[4], wl[128];

    // softmax over all 2048 (each thread owns s = i*256+t)
    float v[8];
    float mx = -1e30f;
#pragma unroll
    for (int i = 0; i < 8; ++i) {
        int s = i * 256 + t;
        float x = 0.f;
#pragma unroll
        for (int p = 0; p < 8; ++p)
            x += part[p * (NB * S_LEN) + b * S_LEN + s];
        v[i] = x;
        mx = fmaxf(mx, x);
    }
#pragma unroll
    for (int d = 1; d < 64; d <<= 1) mx = fmaxf(mx, __shfl_xor(mx, d, 64));
    if ((t & 63) == 0) sm[t >> 6] = mx;
    __syncthreads();
    mx = fmaxf(fmaxf(sm[0], sm[1]), fmaxf(sm[2], sm[3]));
    float sum = 0.f;
#pragma unroll
    for (int i = 0; i < 8; ++i) {
        v[i] = __expf(v[i] - mx);
        sum += v[i];
    }
#pragma unroll
    for (int d = 1; d < 64; d <<= 1) sum += __shfl_xor(sum, d, 64);
    if ((t & 63) == 0) ss[t >> 6] = sum;
    __syncthreads();
    sum = ss[0] + ss[1] + ss[2] + ss[3];
    float inv = 1.0f / sum;

    // stash this block's 128-s window of weights; write d_out from sc==0
    if ((t >> 7) == (sc & 1)) wl[t & 127] = v[sc >> 1] * inv;
    if (sc == 0) {
#pragma unroll
        for (int i = 0; i < 8; ++i)
            weights[b * S_LEN + i * 256 + t] = v[i] * inv;
    }
    __syncthreads();

    // context partial over this s-window (f32 emb)
    int par = t >> 7;
    int e0 = (t & 127) * 8;
    float acc[8] = {};
    for (int i = 0; i < 128; i += 2) {
        int s = sc * 128 + i + par;
        float w = wl[i + par];
        const float* ep = emb + (((size_t)(s * NB + b)) << 10) + e0;
        f32x4 x0 = *(const f32x4*)ep;
        f32x4 x1 = *(const f32x4*)(ep + 4);
        acc[0] += w * x0[0]; acc[1] += w * x0[1];
        acc[2] += w * x0[2]; acc[3] += w * x0[3];
        acc[4] += w * x1[0]; acc[5] += w * x1[1];
        acc[6] += w * x1[2]; acc[7] += w * x1[3];
    }
    float* dst = cpart + ((size_t)(sc * 2 + par) * NB + b) * EMB + e0;
    f32x4 lo = {acc[0], acc[1], acc[2], acc[3]};
    f32x4 hi = {acc[4], acc[5], acc[6], acc[7]};
    *(f32x4*)(dst)     = lo;
    *(f32x4*)(dst + 4) = hi;
}

// ---------------- K_ctx2: reduce 32 partials -> context (d_out front)
__global__ void k_ctx2(const float* __restrict__ cpart, float* __restrict__ ctx) {
    int i = blockIdx.x * 256 + threadIdx.x;   // 32*1024
    float s = 0.f;
#pragma unroll
    for (int p = 0; p < 32; ++p) s += cpart[(size_t)p * (NB * EMB) + i];
    ctx[i] = s;
}

extern "C" void kernel_launch(void* const* d_in, const int* in_sizes, int n_in,
                              void* d_out, int out_size, void* d_ws, size_t ws_size,
                              hipStream_t stream) {
    const float* hid   = (const float*)d_in[0];
    const float* emb   = (const float*)d_in[1];
    const float* W_hid = (const float*)d_in[2];
    const float* b_hid = (const float*)d_in[3];
    const float* W_emb = (const float*)d_in[4];
    const float* b_emb = (const float*)d_in[5];
    const float* att_v = (const float*)d_in[6];

    float* out     = (float*)d_out;
    float* ctx     = out;                // 32*1024
    float* weights = out + NB * EMB;     // 32*2048

    char* ws = (char*)d_ws;
    float*          part     = (float*)(ws);                    // 2 MiB
    float*          hid_comb = (float*)(ws + 2097152);          // 64 KiB
    unsigned short* WT       = (unsigned short*)(ws + 2162688); // 1 MiB
    float*          cpart    = (float*)(ws + 3211264);          // 4 MiB

    k_hw<<<576, 256, 0, stream>>>(hid, W_hid, b_hid, W_emb, b_emb, hid_comb, WT);
    k_gemm_scores<<<512, 512, 0, stream>>>(emb, WT, hid_comb, att_v, part);
    k_ctx1s<<<dim3(16, NB), 256, 0, stream>>>(emb, part, weights, cpart);
    k_ctx2<<<128, 256, 0, stream>>>(cpart, ctx);
}